// Round 1
// baseline (22680.823 us; speedup 1.0000x reference)
//
#include <hip/hip_runtime.h>
#include <cmath>
#include <cstdint>

// GPT-2 (124M) forward: B=2, T=1024, C=768, H=12, L=12, V=50257, D=64
#define T_SEQ 1024
#define NH 12
#define NL 12
#define NV 50257
#define CD 768
#define M_ROWS 2048   // B*T

typedef __bf16 bf16_t;
typedef __bf16 bf16x8 __attribute__((ext_vector_type(8)));
typedef float f32x4 __attribute__((ext_vector_type(4)));

// ---------------------------------------------------------------- embedding
__global__ __launch_bounds__(256) void embed_k(const int* __restrict__ idx,
    const float* __restrict__ wte, const float* __restrict__ wpe,
    float* __restrict__ x) {
  int m = blockIdx.x;              // b*T + t
  int t = m & (T_SEQ - 1);
  int tok = idx[m];
  const float* a = wte + (size_t)tok * CD;
  const float* p = wpe + (size_t)t * CD;
  float* xr = x + (size_t)m * CD;
  int c = threadIdx.x;
  xr[c]       = a[c]       + p[c];
  xr[c + 256] = a[c + 256] + p[c + 256];
  xr[c + 512] = a[c + 512] + p[c + 512];
}

// ------------------------------------------------------- f32 -> bf16 convert
__global__ __launch_bounds__(256) void cvt_k(const float* __restrict__ in,
    bf16_t* __restrict__ out, int n4) {
  int i = blockIdx.x * 256 + threadIdx.x;
  if (i < n4) {
    float4 v = ((const float4*)in)[i];
    bf16_t* o = out + (size_t)i * 4;
    o[0] = (bf16_t)v.x; o[1] = (bf16_t)v.y;
    o[2] = (bf16_t)v.z; o[3] = (bf16_t)v.w;
  }
}

// ----------------------------------- W[K,N] f32  ->  WT[N,K] bf16 (transpose)
__global__ __launch_bounds__(256) void transcvt_k(const float* __restrict__ W,
    bf16_t* __restrict__ WT, int K, int N) {
  __shared__ float tl[32][33];
  int k0 = blockIdx.y * 32, n0 = blockIdx.x * 32;
  int j = threadIdx.x & 31, i0 = threadIdx.x >> 5;
  #pragma unroll
  for (int i = i0; i < 32; i += 8) tl[i][j] = W[(size_t)(k0 + i) * N + n0 + j];
  __syncthreads();
  #pragma unroll
  for (int i = i0; i < 32; i += 8)
    WT[(size_t)(n0 + i) * K + k0 + j] = (bf16_t)tl[j][i];
}

// ------------------------------------------------------------- LayerNorm
// x f32 [M,768] -> out bf16 [M,768], one block per row, biased variance
__global__ __launch_bounds__(256) void ln_k(const float* __restrict__ x,
    const float* __restrict__ w, const float* __restrict__ bi,
    bf16_t* __restrict__ out) {
  int row = blockIdx.x;
  const float* xr = x + (size_t)row * CD;
  int t = threadIdx.x;
  float v0 = xr[t], v1 = xr[t + 256], v2 = xr[t + 512];
  float s = v0 + v1 + v2;
  float ss = v0 * v0 + v1 * v1 + v2 * v2;
  #pragma unroll
  for (int o = 1; o < 64; o <<= 1) { s += __shfl_xor(s, o); ss += __shfl_xor(ss, o); }
  __shared__ float sh[8];
  int wid = t >> 6, lane = t & 63;
  if (lane == 0) { sh[wid] = s; sh[4 + wid] = ss; }
  __syncthreads();
  s  = sh[0] + sh[1] + sh[2] + sh[3];
  ss = sh[4] + sh[5] + sh[6] + sh[7];
  float mean = s * (1.f / CD);
  float var  = ss * (1.f / CD) - mean * mean;
  float rs = rsqrtf(var + 1e-5f);
  bf16_t* orow = out + (size_t)row * CD;
  orow[t]       = (bf16_t)((v0 - mean) * rs * w[t]       + bi[t]);
  orow[t + 256] = (bf16_t)((v1 - mean) * rs * w[t + 256] + bi[t + 256]);
  orow[t + 512] = (bf16_t)((v2 - mean) * rs * w[t + 512] + bi[t + 512]);
}

// ------------------------------------------------------------- GEMM (B^T)
// out[m,n] = sum_k A[m,k]*BT[n,k] (+bias) with epilogue
// EPI 0: +bias -> bf16 | 1: gelu(+bias) -> bf16 | 2: +bias+resid -> f32 | 3: plain f32
// 256 threads = 4 waves (2x2), wave tile (BM/2)x(BN/2), MFMA 16x16x32 bf16.
template <int BM, int BN, int EPI>
__global__ __launch_bounds__(256) void gemm_bt(
    const bf16_t* __restrict__ A,     // [M,K]
    const bf16_t* __restrict__ BT,    // [N,K]
    const float* __restrict__ bias,   // [N] or null
    const float* __restrict__ resid,  // [M,N] or null
    void* __restrict__ out_p,
    int Mdim, int Ndim, int Kdim) {
  constexpr int MR = BM / 32, NR = BN / 32;   // 16x16 frags per wave
  __shared__ bf16_t As[BM * 32];
  __shared__ bf16_t Bs[BN * 32];
  const int t = threadIdx.x;
  const int wid = t >> 6, lane = t & 63;
  const int wm = wid >> 1, wn = wid & 1;
  const int m0 = blockIdx.y * BM, n0 = blockIdx.x * BN;

  f32x4 acc[MR][NR] = {};

  for (int kt = 0; kt < Kdim; kt += 32) {
    // stage A tile [BM][32] bf16 (reg-staged, 16B chunks)
    #pragma unroll
    for (int c = t; c < BM * 4; c += 256) {
      int row = c >> 2, k8 = (c & 3) * 8;
      *(bf16x8*)&As[c * 8] =
          *(const bf16x8*)(A + (size_t)(m0 + row) * Kdim + kt + k8);
    }
    // stage B tile [BN][32] bf16 (clamp row for ragged N in lm_head)
    #pragma unroll
    for (int c = t; c < BN * 4; c += 256) {
      int row = c >> 2, k8 = (c & 3) * 8;
      int nr = n0 + row; if (nr >= Ndim) nr = Ndim - 1;
      *(bf16x8*)&Bs[c * 8] =
          *(const bf16x8*)(BT + (size_t)nr * Kdim + kt + k8);
    }
    __syncthreads();

    bf16x8 af[MR], bf[NR];
    #pragma unroll
    for (int mm = 0; mm < MR; ++mm)
      af[mm] = *(const bf16x8*)&As[(wm * (BM / 2) + mm * 16 + (lane & 15)) * 32 + (lane >> 4) * 8];
    #pragma unroll
    for (int nn = 0; nn < NR; ++nn)
      bf[nn] = *(const bf16x8*)&Bs[(wn * (BN / 2) + nn * 16 + (lane & 15)) * 32 + (lane >> 4) * 8];
    #pragma unroll
    for (int mm = 0; mm < MR; ++mm)
      #pragma unroll
      for (int nn = 0; nn < NR; ++nn)
        acc[mm][nn] = __builtin_amdgcn_mfma_f32_16x16x32_bf16(af[mm], bf[nn], acc[mm][nn], 0, 0, 0);
    __syncthreads();
  }

  // epilogue: D layout col=lane&15, row=(lane>>4)*4+r
  bf16_t* ob = (bf16_t*)out_p;
  float*  of = (float*)out_p;
  const int row0 = m0 + wm * (BM / 2);
  const int col0 = n0 + wn * (BN / 2);
  #pragma unroll
  for (int mm = 0; mm < MR; ++mm) {
    #pragma unroll
    for (int nn = 0; nn < NR; ++nn) {
      int col = col0 + nn * 16 + (lane & 15);
      if (col >= Ndim) continue;
      float bv = (EPI != 3) ? bias[col] : 0.f;
      #pragma unroll
      for (int r = 0; r < 4; ++r) {
        int row = row0 + mm * 16 + (lane >> 4) * 4 + r;
        float v = acc[mm][nn][r] + bv;
        size_t o = (size_t)row * Ndim + col;
        if (EPI == 0) {
          ob[o] = (bf16_t)v;
        } else if (EPI == 1) {
          float u = v + 0.044715f * v * v * v;
          v = 0.5f * v * (1.f + tanhf(0.79788456080286536f * u));
          ob[o] = (bf16_t)v;
        } else if (EPI == 2) {
          of[o] = resid[o] + v;
        } else {
          of[o] = v;
        }
      }
    }
  }
}

// ------------------------------------------------------------- attention
// qkv bf16 [2048, 3*768]; one wave handles 4 consecutive q rows of one (b,h).
// lane = d (D=64 == wave size). Online softmax, f32 math.
__global__ __launch_bounds__(256) void attn_k(const bf16_t* __restrict__ qkv,
                                              bf16_t* __restrict__ y) {
  int wid = threadIdx.x >> 6, lane = threadIdx.x & 63;
  int gw = blockIdx.x * 4 + wid;             // 0 .. B*H*T/4-1
  int q0 = (gw & (T_SEQ / 4 - 1)) * 4;
  int bh = gw >> 8;                          // /(T/4)
  int h = bh % NH, b = bh / NH;
  const size_t base = (size_t)(b * T_SEQ) * (3 * CD) + h * 64 + lane;
  const bf16_t* Q  = qkv + base;
  const bf16_t* Kp = qkv + base + CD;
  const bf16_t* Vp = qkv + base + 2 * CD;

  float qv[4], m_[4], l_[4], acc[4];
  #pragma unroll
  for (int i = 0; i < 4; ++i) {
    qv[i] = (float)Q[(size_t)(q0 + i) * (3 * CD)] * 0.125f;  // 1/sqrt(64)
    m_[i] = -INFINITY; l_[i] = 0.f; acc[i] = 0.f;
  }
  for (int k = 0; k <= q0 + 3; ++k) {
    float kd = (float)Kp[(size_t)k * (3 * CD)];
    float vd = (float)Vp[(size_t)k * (3 * CD)];
    #pragma unroll
    for (int i = 0; i < 4; ++i) {
      float s = qv[i] * kd;
      s += __shfl_xor(s, 1);  s += __shfl_xor(s, 2);  s += __shfl_xor(s, 4);
      s += __shfl_xor(s, 8);  s += __shfl_xor(s, 16); s += __shfl_xor(s, 32);
      if (k <= q0 + i) {
        float mn = fmaxf(m_[i], s);
        float p  = __expf(s - mn);
        float al = __expf(m_[i] - mn);
        l_[i]  = l_[i] * al + p;
        acc[i] = acc[i] * al + p * vd;
        m_[i]  = mn;
      }
    }
  }
  #pragma unroll
  for (int i = 0; i < 4; ++i)
    y[(size_t)(b * T_SEQ + q0 + i) * CD + h * 64 + lane] = (bf16_t)(acc[i] / l_[i]);
}

// ---------------------------------------------------------------- launcher
extern "C" void kernel_launch(void* const* d_in, const int* in_sizes, int n_in,
                              void* d_out, int out_size, void* d_ws, size_t ws_size,
                              hipStream_t stream) {
  const int*   idx   = (const int*)d_in[0];
  const float* wte   = (const float*)d_in[1];
  const float* wpe   = (const float*)d_in[2];
  const float* ln1w  = (const float*)d_in[3];
  const float* ln1b  = (const float*)d_in[4];
  const float* qkvw  = (const float*)d_in[5];
  const float* qkvb  = (const float*)d_in[6];
  const float* projw = (const float*)d_in[7];
  const float* projb = (const float*)d_in[8];
  const float* ln2w  = (const float*)d_in[9];
  const float* ln2b  = (const float*)d_in[10];
  const float* fcw   = (const float*)d_in[11];
  const float* fcb   = (const float*)d_in[12];
  const float* fcow  = (const float*)d_in[13];
  const float* fcob  = (const float*)d_in[14];
  const float* lnfw  = (const float*)d_in[15];
  const float* lnfb  = (const float*)d_in[16];
  float* out = (float*)d_out;

  // workspace carve (~132 MB total)
  char* w = (char*)d_ws;
  auto alloc = [&](size_t bytes) {
    char* p = w; w += (bytes + 255) & ~(size_t)255; return p;
  };
  float*  x    = (float*)alloc((size_t)M_ROWS * CD * 4);
  float*  x2   = (float*)alloc((size_t)M_ROWS * CD * 4);
  bf16_t* hb   = (bf16_t*)alloc((size_t)M_ROWS * CD * 2);
  bf16_t* qkvB = (bf16_t*)alloc((size_t)M_ROWS * 3 * CD * 2);
  bf16_t* yb   = (bf16_t*)alloc((size_t)M_ROWS * CD * 2);
  bf16_t* fca  = (bf16_t*)alloc((size_t)M_ROWS * 4 * CD * 2);
  bf16_t* wqT  = (bf16_t*)alloc((size_t)3 * CD * CD * 2);   // [2304][768]
  bf16_t* wpT  = (bf16_t*)alloc((size_t)CD * CD * 2);       // [768][768]
  bf16_t* wfT  = (bf16_t*)alloc((size_t)4 * CD * CD * 2);   // [3072][768]
  bf16_t* woT  = (bf16_t*)alloc((size_t)CD * 4 * CD * 2);   // [768][3072]
  bf16_t* wteB = (bf16_t*)alloc((size_t)NV * CD * 2);       // [50257][768]

  embed_k<<<M_ROWS, 256, 0, stream>>>(idx, wte, wpe, x);
  {
    int n4 = NV * CD / 4;
    cvt_k<<<(n4 + 255) / 256, 256, 0, stream>>>(wte, wteB, n4);
  }

  for (int l = 0; l < NL; ++l) {
    transcvt_k<<<dim3(3 * CD / 32, CD / 32),     256, 0, stream>>>(qkvw  + (size_t)l * CD * 3 * CD, wqT, CD, 3 * CD);
    transcvt_k<<<dim3(CD / 32, CD / 32),         256, 0, stream>>>(projw + (size_t)l * CD * CD,     wpT, CD, CD);
    transcvt_k<<<dim3(4 * CD / 32, CD / 32),     256, 0, stream>>>(fcw   + (size_t)l * CD * 4 * CD, wfT, CD, 4 * CD);
    transcvt_k<<<dim3(CD / 32, 4 * CD / 32),     256, 0, stream>>>(fcow  + (size_t)l * 4 * CD * CD, woT, 4 * CD, CD);

    ln_k<<<M_ROWS, 256, 0, stream>>>(x, ln1w + l * CD, ln1b + l * CD, hb);
    gemm_bt<128, 128, 0><<<dim3(3 * CD / 128, M_ROWS / 128), 256, 0, stream>>>(
        hb, wqT, qkvb + l * 3 * CD, nullptr, qkvB, M_ROWS, 3 * CD, CD);
    attn_k<<<2 * NH * T_SEQ / 16, 256, 0, stream>>>(qkvB, yb);
    gemm_bt<64, 64, 2><<<dim3(CD / 64, M_ROWS / 64), 256, 0, stream>>>(
        yb, wpT, projb + l * CD, x, x2, M_ROWS, CD, CD);
    ln_k<<<M_ROWS, 256, 0, stream>>>(x2, ln2w + l * CD, ln2b + l * CD, hb);
    gemm_bt<128, 128, 1><<<dim3(4 * CD / 128, M_ROWS / 128), 256, 0, stream>>>(
        hb, wfT, fcb + l * 4 * CD, nullptr, fca, M_ROWS, 4 * CD, CD);
    gemm_bt<64, 64, 2><<<dim3(CD / 64, M_ROWS / 64), 256, 0, stream>>>(
        fca, woT, fcob + l * CD, x2, x, M_ROWS, CD, 4 * CD);
  }

  ln_k<<<M_ROWS, 256, 0, stream>>>(x, lnfw, lnfb, hb);
  gemm_bt<128, 128, 3><<<dim3((NV + 127) / 128, M_ROWS / 128), 256, 0, stream>>>(
      hb, wteB, nullptr, nullptr, out, M_ROWS, NV, CD);
}

// Round 2
// 2960.824 us; speedup vs baseline: 7.6603x; 7.6603x over previous
//
#include <hip/hip_runtime.h>
#include <cmath>
#include <cstdint>

// GPT-2 (124M) forward: B=2, T=1024, C=768, H=12, L=12, V=50257, D=64
#define T_SEQ 1024
#define NH 12
#define NL 12
#define NV 50257
#define CD 768
#define M_ROWS 2048   // B*T

typedef __bf16 bf16_t;
typedef __bf16 bf16x8 __attribute__((ext_vector_type(8)));
typedef float f32x4 __attribute__((ext_vector_type(4)));

// ---------------------------------------------------------------- embedding
__global__ __launch_bounds__(256) void embed_k(const int* __restrict__ idx,
    const float* __restrict__ wte, const float* __restrict__ wpe,
    float* __restrict__ x) {
  int m = blockIdx.x;              // b*T + t
  int t = m & (T_SEQ - 1);
  int tok = idx[m];
  const float* a = wte + (size_t)tok * CD;
  const float* p = wpe + (size_t)t * CD;
  float* xr = x + (size_t)m * CD;
  int c = threadIdx.x;
  xr[c]       = a[c]       + p[c];
  xr[c + 256] = a[c + 256] + p[c + 256];
  xr[c + 512] = a[c + 512] + p[c + 512];
}

// ------------------------------------------------------- f32 -> bf16 convert
__global__ __launch_bounds__(256) void cvt_k(const float* __restrict__ in,
    bf16_t* __restrict__ out, int n4) {
  int i = blockIdx.x * 256 + threadIdx.x;
  if (i < n4) {
    float4 v = ((const float4*)in)[i];
    bf16_t* o = out + (size_t)i * 4;
    o[0] = (bf16_t)v.x; o[1] = (bf16_t)v.y;
    o[2] = (bf16_t)v.z; o[3] = (bf16_t)v.w;
  }
}

// ----------------------------------- W[K,N] f32  ->  WT[N,K] bf16 (transpose)
__global__ __launch_bounds__(256) void transcvt_k(const float* __restrict__ W,
    bf16_t* __restrict__ WT, int K, int N) {
  __shared__ float tl[32][33];
  int k0 = blockIdx.y * 32, n0 = blockIdx.x * 32;
  int j = threadIdx.x & 31, i0 = threadIdx.x >> 5;
  #pragma unroll
  for (int i = i0; i < 32; i += 8) tl[i][j] = W[(size_t)(k0 + i) * N + n0 + j];
  __syncthreads();
  #pragma unroll
  for (int i = i0; i < 32; i += 8)
    WT[(size_t)(n0 + i) * K + k0 + j] = (bf16_t)tl[j][i];
}

// ------------------------------------------------------------- LayerNorm
__global__ __launch_bounds__(256) void ln_k(const float* __restrict__ x,
    const float* __restrict__ w, const float* __restrict__ bi,
    bf16_t* __restrict__ out) {
  int row = blockIdx.x;
  const float* xr = x + (size_t)row * CD;
  int t = threadIdx.x;
  float v0 = xr[t], v1 = xr[t + 256], v2 = xr[t + 512];
  float s = v0 + v1 + v2;
  float ss = v0 * v0 + v1 * v1 + v2 * v2;
  #pragma unroll
  for (int o = 1; o < 64; o <<= 1) { s += __shfl_xor(s, o); ss += __shfl_xor(ss, o); }
  __shared__ float sh[8];
  int wid = t >> 6, lane = t & 63;
  if (lane == 0) { sh[wid] = s; sh[4 + wid] = ss; }
  __syncthreads();
  s  = sh[0] + sh[1] + sh[2] + sh[3];
  ss = sh[4] + sh[5] + sh[6] + sh[7];
  float mean = s * (1.f / CD);
  float var  = ss * (1.f / CD) - mean * mean;
  float rs = rsqrtf(var + 1e-5f);
  bf16_t* orow = out + (size_t)row * CD;
  orow[t]       = (bf16_t)((v0 - mean) * rs * w[t]       + bi[t]);
  orow[t + 256] = (bf16_t)((v1 - mean) * rs * w[t + 256] + bi[t + 256]);
  orow[t + 512] = (bf16_t)((v2 - mean) * rs * w[t + 512] + bi[t + 512]);
}

// ------------------------------------------------------------- GEMM (B^T)
// EPI 0: +bias -> bf16 | 1: gelu(+bias) -> bf16 | 2: +bias+resid -> f32 | 3: plain f32
template <int BM, int BN, int EPI>
__global__ __launch_bounds__(256) void gemm_bt(
    const bf16_t* __restrict__ A,     // [M,K]
    const bf16_t* __restrict__ BT,    // [N,K]
    const float* __restrict__ bias,   // [N] or null
    const float* __restrict__ resid,  // [M,N] or null
    void* __restrict__ out_p,
    int Mdim, int Ndim, int Kdim) {
  constexpr int MR = BM / 32, NR = BN / 32;
  __shared__ bf16_t As[BM * 32];
  __shared__ bf16_t Bs[BN * 32];
  const int t = threadIdx.x;
  const int wid = t >> 6, lane = t & 63;
  const int wm = wid >> 1, wn = wid & 1;
  const int m0 = blockIdx.y * BM, n0 = blockIdx.x * BN;

  f32x4 acc[MR][NR] = {};

  for (int kt = 0; kt < Kdim; kt += 32) {
    #pragma unroll
    for (int c = t; c < BM * 4; c += 256) {
      int row = c >> 2, k8 = (c & 3) * 8;
      *(bf16x8*)&As[c * 8] =
          *(const bf16x8*)(A + (size_t)(m0 + row) * Kdim + kt + k8);
    }
    #pragma unroll
    for (int c = t; c < BN * 4; c += 256) {
      int row = c >> 2, k8 = (c & 3) * 8;
      int nr = n0 + row; if (nr >= Ndim) nr = Ndim - 1;
      *(bf16x8*)&Bs[c * 8] =
          *(const bf16x8*)(BT + (size_t)nr * Kdim + kt + k8);
    }
    __syncthreads();

    bf16x8 af[MR], bfr[NR];
    #pragma unroll
    for (int mm = 0; mm < MR; ++mm)
      af[mm] = *(const bf16x8*)&As[(wm * (BM / 2) + mm * 16 + (lane & 15)) * 32 + (lane >> 4) * 8];
    #pragma unroll
    for (int nn = 0; nn < NR; ++nn)
      bfr[nn] = *(const bf16x8*)&Bs[(wn * (BN / 2) + nn * 16 + (lane & 15)) * 32 + (lane >> 4) * 8];
    #pragma unroll
    for (int mm = 0; mm < MR; ++mm)
      #pragma unroll
      for (int nn = 0; nn < NR; ++nn)
        acc[mm][nn] = __builtin_amdgcn_mfma_f32_16x16x32_bf16(af[mm], bfr[nn], acc[mm][nn], 0, 0, 0);
    __syncthreads();
  }

  bf16_t* ob = (bf16_t*)out_p;
  float*  of = (float*)out_p;
  const int row0 = m0 + wm * (BM / 2);
  const int col0 = n0 + wn * (BN / 2);
  #pragma unroll
  for (int mm = 0; mm < MR; ++mm) {
    #pragma unroll
    for (int nn = 0; nn < NR; ++nn) {
      int col = col0 + nn * 16 + (lane & 15);
      if (col >= Ndim) continue;
      float bv = (EPI != 3) ? bias[col] : 0.f;
      #pragma unroll
      for (int r = 0; r < 4; ++r) {
        int row = row0 + mm * 16 + (lane >> 4) * 4 + r;
        float v = acc[mm][nn][r] + bv;
        size_t o = (size_t)row * Ndim + col;
        if (EPI == 0) {
          ob[o] = (bf16_t)v;
        } else if (EPI == 1) {
          float u = v + 0.044715f * v * v * v;
          v = 0.5f * v * (1.f + tanhf(0.79788456080286536f * u));
          ob[o] = (bf16_t)v;
        } else if (EPI == 2) {
          of[o] = resid[o] + v;
        } else {
          of[o] = v;
        }
      }
    }
  }
}

// --------------------------------------------- V transpose: VT[bh][64][1024]
// from qkv bf16 [2048, 2304] V part (cols 1536..2303)
__global__ __launch_bounds__(256) void vtrans_k(const bf16_t* __restrict__ qkv,
                                                bf16_t* __restrict__ VT) {
  __shared__ __align__(16) bf16_t tl[64 * 72];   // [d][t], stride 72 elems (144B)
  const int bh = blockIdx.y;                     // b*NH + h
  const int t0 = blockIdx.x * 64;
  const int b = bh / NH, h = bh % NH;
  const int tid = threadIdx.x;
  const int row = tid >> 2;                      // t-row 0..63 (load) / d-row (store)
  const int seg = (tid & 3) * 16;                // d-seg (load) / t-seg (store)

  const bf16_t* src = qkv + (size_t)(b * T_SEQ + t0 + row) * (3 * CD) + 2 * CD + h * 64 + seg;
  bf16x8 v0 = *(const bf16x8*)src;
  bf16x8 v1 = *(const bf16x8*)(src + 8);
  #pragma unroll
  for (int j = 0; j < 8; ++j) tl[(seg + j) * 72 + row] = v0[j];
  #pragma unroll
  for (int j = 0; j < 8; ++j) tl[(seg + 8 + j) * 72 + row] = v1[j];
  __syncthreads();

  bf16_t* dst = VT + ((size_t)bh * 64 + row) * T_SEQ + t0 + seg;
  *(bf16x8*)dst       = *(const bf16x8*)&tl[row * 72 + seg];
  *(bf16x8*)(dst + 8) = *(const bf16x8*)&tl[row * 72 + seg + 8];
}

// ------------------------------------------------------- MFMA flash attention
// 1 wave/block. Each wave: Q-tile pair (qi, 63-qi) of one (b,h) -> uniform load.
// QK^T and PV via mfma_f32_16x16x32_bf16; online softmax f32.
__global__ __launch_bounds__(64) void attn_k(const bf16_t* __restrict__ qkv,
                                             const bf16_t* __restrict__ VT,
                                             bf16_t* __restrict__ y) {
  __shared__ __align__(16) bf16_t Ps[16 * 40];   // P tile, row stride 40 elems (80B)
  const int lane = threadIdx.x;
  const int gw = blockIdx.x;                     // 0 .. B*NH*32-1
  const int pi = gw & 31;
  const int bh = gw >> 5;
  const int h = bh % NH, b = bh / NH;
  const bf16_t* Qbase = qkv + (size_t)b * T_SEQ * (3 * CD) + h * 64;
  const bf16_t* Kbase = Qbase + CD;
  const bf16_t* Vt = VT + (size_t)bh * 64 * T_SEQ;

  const int l15 = lane & 15, lhi = lane >> 4;

  #pragma unroll
  for (int half = 0; half < 2; ++half) {
    const int qi = half ? (63 - pi) : pi;
    const int q0 = qi * 16;

    bf16x8 aq[2];
    #pragma unroll
    for (int c = 0; c < 2; ++c)
      aq[c] = *(const bf16x8*)(Qbase + (size_t)(q0 + l15) * (3 * CD) + c * 32 + lhi * 8);

    f32x4 acc[4] = {};
    float m_[4], l_[4];
    #pragma unroll
    for (int r = 0; r < 4; ++r) { m_[r] = -INFINITY; l_[r] = 0.f; }

    const int qrow = q0 + lhi * 4;           // + r
    const int nt = (q0 + 47) / 32;
    for (int kt = 0; kt < nt; ++kt) {
      const int k0 = kt * 32;
      // ---- QK^T
      f32x4 s[2] = {};
      #pragma unroll
      for (int c = 0; c < 2; ++c) {
        #pragma unroll
        for (int kc = 0; kc < 2; ++kc) {
          bf16x8 bk = *(const bf16x8*)(Kbase + (size_t)(k0 + kc * 16 + l15) * (3 * CD) + c * 32 + lhi * 8);
          s[kc] = __builtin_amdgcn_mfma_f32_16x16x32_bf16(aq[c], bk, s[kc], 0, 0, 0);
        }
      }
      // ---- scale + causal mask + row max
      float mx[4];
      #pragma unroll
      for (int r = 0; r < 4; ++r) mx[r] = -INFINITY;
      #pragma unroll
      for (int kc = 0; kc < 2; ++kc) {
        const int kcol = k0 + kc * 16 + l15;
        #pragma unroll
        for (int r = 0; r < 4; ++r) {
          float sv = (kcol <= qrow + r) ? s[kc][r] * 0.125f : -INFINITY;
          s[kc][r] = sv;
          mx[r] = fmaxf(mx[r], sv);
        }
      }
      #pragma unroll
      for (int r = 0; r < 4; ++r) {
        mx[r] = fmaxf(mx[r], __shfl_xor(mx[r], 1));
        mx[r] = fmaxf(mx[r], __shfl_xor(mx[r], 2));
        mx[r] = fmaxf(mx[r], __shfl_xor(mx[r], 4));
        mx[r] = fmaxf(mx[r], __shfl_xor(mx[r], 8));
      }
      // ---- online softmax update
      float al[4], rs[4];
      #pragma unroll
      for (int r = 0; r < 4; ++r) {
        float mn = fmaxf(m_[r], mx[r]);
        al[r] = __expf(m_[r] - mn);
        m_[r] = mn;
        float p0 = __expf(s[0][r] - mn);
        float p1 = __expf(s[1][r] - mn);
        s[0][r] = p0; s[1][r] = p1;
        rs[r] = p0 + p1;
      }
      #pragma unroll
      for (int r = 0; r < 4; ++r) {
        rs[r] += __shfl_xor(rs[r], 1);
        rs[r] += __shfl_xor(rs[r], 2);
        rs[r] += __shfl_xor(rs[r], 4);
        rs[r] += __shfl_xor(rs[r], 8);
        l_[r] = l_[r] * al[r] + rs[r];
      }
      #pragma unroll
      for (int dt = 0; dt < 4; ++dt)
        #pragma unroll
        for (int r = 0; r < 4; ++r) acc[dt][r] *= al[r];
      // ---- P -> LDS (bf16), reload as A-fragments
      #pragma unroll
      for (int kc = 0; kc < 2; ++kc)
        #pragma unroll
        for (int r = 0; r < 4; ++r)
          Ps[(lhi * 4 + r) * 40 + kc * 16 + l15] = (bf16_t)s[kc][r];
      bf16x8 pa = *(const bf16x8*)&Ps[l15 * 40 + lhi * 8];
      // ---- PV
      #pragma unroll
      for (int dt = 0; dt < 4; ++dt) {
        bf16x8 bv = *(const bf16x8*)(Vt + (size_t)(dt * 16 + l15) * T_SEQ + k0 + lhi * 8);
        acc[dt] = __builtin_amdgcn_mfma_f32_16x16x32_bf16(pa, bv, acc[dt], 0, 0, 0);
      }
    }
    // ---- write y
    #pragma unroll
    for (int dt = 0; dt < 4; ++dt)
      #pragma unroll
      for (int r = 0; r < 4; ++r)
        y[(size_t)(b * T_SEQ + q0 + lhi * 4 + r) * CD + h * 64 + dt * 16 + l15] =
            (bf16_t)(acc[dt][r] / l_[r]);
  }
}

// ---------------------------------------------------------------- launcher
extern "C" void kernel_launch(void* const* d_in, const int* in_sizes, int n_in,
                              void* d_out, int out_size, void* d_ws, size_t ws_size,
                              hipStream_t stream) {
  const int*   idx   = (const int*)d_in[0];
  const float* wte   = (const float*)d_in[1];
  const float* wpe   = (const float*)d_in[2];
  const float* ln1w  = (const float*)d_in[3];
  const float* ln1b  = (const float*)d_in[4];
  const float* qkvw  = (const float*)d_in[5];
  const float* qkvb  = (const float*)d_in[6];
  const float* projw = (const float*)d_in[7];
  const float* projb = (const float*)d_in[8];
  const float* ln2w  = (const float*)d_in[9];
  const float* ln2b  = (const float*)d_in[10];
  const float* fcw   = (const float*)d_in[11];
  const float* fcb   = (const float*)d_in[12];
  const float* fcow  = (const float*)d_in[13];
  const float* fcob  = (const float*)d_in[14];
  const float* lnfw  = (const float*)d_in[15];
  const float* lnfb  = (const float*)d_in[16];
  float* out = (float*)d_out;

  char* w = (char*)d_ws;
  auto alloc = [&](size_t bytes) {
    char* p = w; w += (bytes + 255) & ~(size_t)255; return p;
  };
  float*  x    = (float*)alloc((size_t)M_ROWS * CD * 4);
  float*  x2   = (float*)alloc((size_t)M_ROWS * CD * 4);
  bf16_t* hb   = (bf16_t*)alloc((size_t)M_ROWS * CD * 2);
  bf16_t* qkvB = (bf16_t*)alloc((size_t)M_ROWS * 3 * CD * 2);
  bf16_t* yb   = (bf16_t*)alloc((size_t)M_ROWS * CD * 2);
  bf16_t* fca  = (bf16_t*)alloc((size_t)M_ROWS * 4 * CD * 2);
  bf16_t* VT   = (bf16_t*)alloc((size_t)2 * NH * 64 * T_SEQ * 2);
  bf16_t* wqT  = (bf16_t*)alloc((size_t)3 * CD * CD * 2);
  bf16_t* wpT  = (bf16_t*)alloc((size_t)CD * CD * 2);
  bf16_t* wfT  = (bf16_t*)alloc((size_t)4 * CD * CD * 2);
  bf16_t* woT  = (bf16_t*)alloc((size_t)CD * 4 * CD * 2);
  bf16_t* wteB = (bf16_t*)alloc((size_t)NV * CD * 2);

  embed_k<<<M_ROWS, 256, 0, stream>>>(idx, wte, wpe, x);
  {
    int n4 = NV * CD / 4;
    cvt_k<<<(n4 + 255) / 256, 256, 0, stream>>>(wte, wteB, n4);
  }

  for (int l = 0; l < NL; ++l) {
    transcvt_k<<<dim3(3 * CD / 32, CD / 32), 256, 0, stream>>>(qkvw  + (size_t)l * CD * 3 * CD, wqT, CD, 3 * CD);
    transcvt_k<<<dim3(CD / 32, CD / 32),     256, 0, stream>>>(projw + (size_t)l * CD * CD,     wpT, CD, CD);
    transcvt_k<<<dim3(4 * CD / 32, CD / 32), 256, 0, stream>>>(fcw   + (size_t)l * CD * 4 * CD, wfT, CD, 4 * CD);
    transcvt_k<<<dim3(CD / 32, 4 * CD / 32), 256, 0, stream>>>(fcow  + (size_t)l * 4 * CD * CD, woT, 4 * CD, CD);

    ln_k<<<M_ROWS, 256, 0, stream>>>(x, ln1w + l * CD, ln1b + l * CD, hb);
    gemm_bt<128, 128, 0><<<dim3(3 * CD / 128, M_ROWS / 128), 256, 0, stream>>>(
        hb, wqT, qkvb + l * 3 * CD, nullptr, qkvB, M_ROWS, 3 * CD, CD);
    vtrans_k<<<dim3(T_SEQ / 64, 2 * NH), 256, 0, stream>>>(qkvB, VT);
    attn_k<<<2 * NH * 32, 64, 0, stream>>>(qkvB, VT, yb);
    gemm_bt<64, 64, 2><<<dim3(CD / 64, M_ROWS / 64), 256, 0, stream>>>(
        yb, wpT, projb + l * CD, x, x2, M_ROWS, CD, CD);
    ln_k<<<M_ROWS, 256, 0, stream>>>(x2, ln2w + l * CD, ln2b + l * CD, hb);
    gemm_bt<128, 128, 1><<<dim3(4 * CD / 128, M_ROWS / 128), 256, 0, stream>>>(
        hb, wfT, fcb + l * 4 * CD, nullptr, fca, M_ROWS, 4 * CD, CD);
    gemm_bt<64, 64, 2><<<dim3(CD / 64, M_ROWS / 64), 256, 0, stream>>>(
        fca, woT, fcob + l * CD, x2, x, M_ROWS, CD, 4 * CD);
  }

  ln_k<<<M_ROWS, 256, 0, stream>>>(x, lnfw, lnfb, hb);
  gemm_bt<128, 128, 3><<<dim3((NV + 127) / 128, M_ROWS / 128), 256, 0, stream>>>(
      hb, wteB, nullptr, nullptr, out, M_ROWS, NV, CD);
}

// Round 3
// 2584.627 us; speedup vs baseline: 8.7753x; 1.1456x over previous
//
#include <hip/hip_runtime.h>
#include <cmath>
#include <cstdint>

// GPT-2 (124M) forward: B=2, T=1024, C=768, H=12, L=12, V=50257, D=64
#define T_SEQ 1024
#define NH 12
#define NL 12
#define NV 50257
#define CD 768
#define M_ROWS 2048   // B*T

typedef __bf16 bf16_t;
typedef __bf16 bf16x8 __attribute__((ext_vector_type(8)));
typedef float f32x4 __attribute__((ext_vector_type(4)));

// async global->LDS, 16B per lane; LDS dest must be wave-uniform base (lane*16 auto)
__device__ __forceinline__ void gload16(const bf16_t* g, bf16_t* l) {
  __builtin_amdgcn_global_load_lds(
      (const __attribute__((address_space(1))) void*)g,
      (__attribute__((address_space(3))) void*)l, 16, 0, 0);
}

// ---------------------------------------------------------------- embedding
__global__ __launch_bounds__(256) void embed_k(const int* __restrict__ idx,
    const float* __restrict__ wte, const float* __restrict__ wpe,
    float* __restrict__ x) {
  int m = blockIdx.x;
  int t = m & (T_SEQ - 1);
  int tok = idx[m];
  const float* a = wte + (size_t)tok * CD;
  const float* p = wpe + (size_t)t * CD;
  float* xr = x + (size_t)m * CD;
  int c = threadIdx.x;
  xr[c]       = a[c]       + p[c];
  xr[c + 256] = a[c + 256] + p[c + 256];
  xr[c + 512] = a[c + 512] + p[c + 512];
}

// ------------------------------------------------------- f32 -> bf16 convert
__global__ __launch_bounds__(256) void cvt_k(const float* __restrict__ in,
    bf16_t* __restrict__ out, int n4) {
  int i = blockIdx.x * 256 + threadIdx.x;
  if (i < n4) {
    float4 v = ((const float4*)in)[i];
    bf16_t* o = out + (size_t)i * 4;
    o[0] = (bf16_t)v.x; o[1] = (bf16_t)v.y;
    o[2] = (bf16_t)v.z; o[3] = (bf16_t)v.w;
  }
}

// ----------------------------------- W[K,N] f32  ->  WT[N,K] bf16 (transpose)
__global__ __launch_bounds__(256) void transcvt_k(const float* __restrict__ W,
    bf16_t* __restrict__ WT, int K, int N) {
  __shared__ float tl[32][33];
  int k0 = blockIdx.y * 32, n0 = blockIdx.x * 32;
  int j = threadIdx.x & 31, i0 = threadIdx.x >> 5;
  #pragma unroll
  for (int i = i0; i < 32; i += 8) tl[i][j] = W[(size_t)(k0 + i) * N + n0 + j];
  __syncthreads();
  #pragma unroll
  for (int i = i0; i < 32; i += 8)
    WT[(size_t)(n0 + i) * K + k0 + j] = (bf16_t)tl[j][i];
}

// ------------------------------------------------------------- LayerNorm
__global__ __launch_bounds__(256) void ln_k(const float* __restrict__ x,
    const float* __restrict__ w, const float* __restrict__ bi,
    bf16_t* __restrict__ out) {
  int row = blockIdx.x;
  const float* xr = x + (size_t)row * CD;
  int t = threadIdx.x;
  float v0 = xr[t], v1 = xr[t + 256], v2 = xr[t + 512];
  float s = v0 + v1 + v2;
  float ss = v0 * v0 + v1 * v1 + v2 * v2;
  #pragma unroll
  for (int o = 1; o < 64; o <<= 1) { s += __shfl_xor(s, o); ss += __shfl_xor(ss, o); }
  __shared__ float sh[8];
  int wid = t >> 6, lane = t & 63;
  if (lane == 0) { sh[wid] = s; sh[4 + wid] = ss; }
  __syncthreads();
  s  = sh[0] + sh[1] + sh[2] + sh[3];
  ss = sh[4] + sh[5] + sh[6] + sh[7];
  float mean = s * (1.f / CD);
  float var  = ss * (1.f / CD) - mean * mean;
  float rs = rsqrtf(var + 1e-5f);
  bf16_t* orow = out + (size_t)row * CD;
  orow[t]       = (bf16_t)((v0 - mean) * rs * w[t]       + bi[t]);
  orow[t + 256] = (bf16_t)((v1 - mean) * rs * w[t + 256] + bi[t + 256]);
  orow[t + 512] = (bf16_t)((v2 - mean) * rs * w[t + 512] + bi[t + 512]);
}

// ------------------------------------------------------------- GEMM (B^T)
// EPI 0: +bias -> bf16 | 1: gelu(+bias) -> bf16 | 2: +bias+resid -> f32 | 3: plain f32
// global_load_lds staging; chunk-XOR swizzled LDS (pos p = chunk c ^ ((row>>1)&3)),
// achieved by pre-swizzling the per-lane GLOBAL source addr (LDS dest linear).
template <int BM, int BN, int EPI, bool SWAP>
__global__ __launch_bounds__(256) void gemm_bt(
    const bf16_t* __restrict__ A,     // [M,K]
    const bf16_t* __restrict__ BT,    // [N,K]
    const float* __restrict__ bias,   // [N] or null
    const float* __restrict__ resid,  // [M,N] or null
    void* __restrict__ out_p,
    int Mdim, int Ndim, int Kdim) {
  constexpr int MR = BM / 32, NR = BN / 32;
  __shared__ __align__(1024) bf16_t As[BM * 32];
  __shared__ __align__(1024) bf16_t Bs[BN * 32];
  const int t = threadIdx.x;
  const int wid = t >> 6, lane = t & 63;
  const int wm = wid >> 1, wn = wid & 1;
  const int m0 = (SWAP ? blockIdx.x : blockIdx.y) * BM;
  const int n0 = (SWAP ? blockIdx.y : blockIdx.x) * BN;
  const int l15 = lane & 15, lhi = lane >> 4;

  f32x4 acc[MR][NR] = {};

  for (int kt = 0; kt < Kdim; kt += 32) {
    // ---- stage A: wave wid owns rows [wid*BM/4, +BM/4); 16 rows / instr
    #pragma unroll
    for (int i = 0; i < BM / 64; ++i) {
      int rbase = wid * (BM / 4) + i * 16;
      int r = rbase + (lane >> 2);
      int c = (lane & 3) ^ ((r >> 1) & 3);
      gload16(A + (size_t)(m0 + r) * Kdim + kt + c * 8, As + rbase * 32);
    }
    // ---- stage B (row-clamped for ragged N)
    #pragma unroll
    for (int i = 0; i < BN / 64; ++i) {
      int rbase = wid * (BN / 4) + i * 16;
      int r = rbase + (lane >> 2);
      int nr = n0 + r; if (nr >= Ndim) nr = Ndim - 1;
      int c = (lane & 3) ^ ((r >> 1) & 3);
      gload16(BT + (size_t)nr * Kdim + kt + c * 8, Bs + rbase * 32);
    }
    __syncthreads();

    bf16x8 af[MR], bfr[NR];
    #pragma unroll
    for (int mm = 0; mm < MR; ++mm) {
      int ra = wm * (BM / 2) + mm * 16 + l15;
      af[mm] = *(const bf16x8*)&As[ra * 32 + ((lhi ^ (ra >> 1)) & 3) * 8];
    }
    #pragma unroll
    for (int nn = 0; nn < NR; ++nn) {
      int rb = wn * (BN / 2) + nn * 16 + l15;
      bfr[nn] = *(const bf16x8*)&Bs[rb * 32 + ((lhi ^ (rb >> 1)) & 3) * 8];
    }
    #pragma unroll
    for (int mm = 0; mm < MR; ++mm)
      #pragma unroll
      for (int nn = 0; nn < NR; ++nn)
        acc[mm][nn] = __builtin_amdgcn_mfma_f32_16x16x32_bf16(af[mm], bfr[nn], acc[mm][nn], 0, 0, 0);
    __syncthreads();
  }

  bf16_t* ob = (bf16_t*)out_p;
  float*  of = (float*)out_p;
  const int row0 = m0 + wm * (BM / 2);
  const int col0 = n0 + wn * (BN / 2);
  #pragma unroll
  for (int mm = 0; mm < MR; ++mm) {
    #pragma unroll
    for (int nn = 0; nn < NR; ++nn) {
      int col = col0 + nn * 16 + l15;
      if (col >= Ndim) continue;
      float bv = (EPI != 3) ? bias[col] : 0.f;
      #pragma unroll
      for (int r = 0; r < 4; ++r) {
        int row = row0 + mm * 16 + lhi * 4 + r;
        float v = acc[mm][nn][r] + bv;
        size_t o = (size_t)row * Ndim + col;
        if (EPI == 0) {
          ob[o] = (bf16_t)v;
        } else if (EPI == 1) {
          float u = v + 0.044715f * v * v * v;
          v = 0.5f * v * (1.f + tanhf(0.79788456080286536f * u));
          ob[o] = (bf16_t)v;
        } else if (EPI == 2) {
          of[o] = resid[o] + v;
        } else {
          of[o] = v;
        }
      }
    }
  }
}

// --------------------------------------------- V transpose: VT[bh][64][1024]
__global__ __launch_bounds__(256) void vtrans_k(const bf16_t* __restrict__ qkv,
                                                bf16_t* __restrict__ VT) {
  __shared__ __align__(16) bf16_t tl[64 * 72];
  const int bh = blockIdx.y;
  const int t0 = blockIdx.x * 64;
  const int b = bh / NH, h = bh % NH;
  const int tid = threadIdx.x;
  const int row = tid >> 2;
  const int seg = (tid & 3) * 16;

  const bf16_t* src = qkv + (size_t)(b * T_SEQ + t0 + row) * (3 * CD) + 2 * CD + h * 64 + seg;
  bf16x8 v0 = *(const bf16x8*)src;
  bf16x8 v1 = *(const bf16x8*)(src + 8);
  #pragma unroll
  for (int j = 0; j < 8; ++j) tl[(seg + j) * 72 + row] = v0[j];
  #pragma unroll
  for (int j = 0; j < 8; ++j) tl[(seg + 8 + j) * 72 + row] = v1[j];
  __syncthreads();

  bf16_t* dst = VT + ((size_t)bh * 64 + row) * T_SEQ + t0 + seg;
  *(bf16x8*)dst       = *(const bf16x8*)&tl[row * 72 + seg];
  *(bf16x8*)(dst + 8) = *(const bf16x8*)&tl[row * 72 + seg + 8];
}

// ------------------------------------------------------- MFMA flash attention
__global__ __launch_bounds__(64) void attn_k(const bf16_t* __restrict__ qkv,
                                             const bf16_t* __restrict__ VT,
                                             bf16_t* __restrict__ y) {
  __shared__ __align__(16) bf16_t Ps[16 * 40];
  const int lane = threadIdx.x;
  const int gw = blockIdx.x;
  const int pi = gw & 31;
  const int bh = gw >> 5;
  const int h = bh % NH, b = bh / NH;
  const bf16_t* Qbase = qkv + (size_t)b * T_SEQ * (3 * CD) + h * 64;
  const bf16_t* Kbase = Qbase + CD;
  const bf16_t* Vt = VT + (size_t)bh * 64 * T_SEQ;

  const int l15 = lane & 15, lhi = lane >> 4;

  #pragma unroll
  for (int half = 0; half < 2; ++half) {
    const int qi = half ? (63 - pi) : pi;
    const int q0 = qi * 16;

    bf16x8 aq[2];
    #pragma unroll
    for (int c = 0; c < 2; ++c)
      aq[c] = *(const bf16x8*)(Qbase + (size_t)(q0 + l15) * (3 * CD) + c * 32 + lhi * 8);

    f32x4 acc[4] = {};
    float m_[4], l_[4];
    #pragma unroll
    for (int r = 0; r < 4; ++r) { m_[r] = -INFINITY; l_[r] = 0.f; }

    const int qrow = q0 + lhi * 4;
    const int nt = (q0 + 47) / 32;
    for (int kt = 0; kt < nt; ++kt) {
      const int k0 = kt * 32;
      f32x4 s[2] = {};
      #pragma unroll
      for (int c = 0; c < 2; ++c) {
        #pragma unroll
        for (int kc = 0; kc < 2; ++kc) {
          bf16x8 bk = *(const bf16x8*)(Kbase + (size_t)(k0 + kc * 16 + l15) * (3 * CD) + c * 32 + lhi * 8);
          s[kc] = __builtin_amdgcn_mfma_f32_16x16x32_bf16(aq[c], bk, s[kc], 0, 0, 0);
        }
      }
      float mx[4];
      #pragma unroll
      for (int r = 0; r < 4; ++r) mx[r] = -INFINITY;
      #pragma unroll
      for (int kc = 0; kc < 2; ++kc) {
        const int kcol = k0 + kc * 16 + l15;
        #pragma unroll
        for (int r = 0; r < 4; ++r) {
          float sv = (kcol <= qrow + r) ? s[kc][r] * 0.125f : -INFINITY;
          s[kc][r] = sv;
          mx[r] = fmaxf(mx[r], sv);
        }
      }
      #pragma unroll
      for (int r = 0; r < 4; ++r) {
        mx[r] = fmaxf(mx[r], __shfl_xor(mx[r], 1));
        mx[r] = fmaxf(mx[r], __shfl_xor(mx[r], 2));
        mx[r] = fmaxf(mx[r], __shfl_xor(mx[r], 4));
        mx[r] = fmaxf(mx[r], __shfl_xor(mx[r], 8));
      }
      float al[4], rs[4];
      #pragma unroll
      for (int r = 0; r < 4; ++r) {
        float mn = fmaxf(m_[r], mx[r]);
        al[r] = __expf(m_[r] - mn);
        m_[r] = mn;
        float p0 = __expf(s[0][r] - mn);
        float p1 = __expf(s[1][r] - mn);
        s[0][r] = p0; s[1][r] = p1;
        rs[r] = p0 + p1;
      }
      #pragma unroll
      for (int r = 0; r < 4; ++r) {
        rs[r] += __shfl_xor(rs[r], 1);
        rs[r] += __shfl_xor(rs[r], 2);
        rs[r] += __shfl_xor(rs[r], 4);
        rs[r] += __shfl_xor(rs[r], 8);
        l_[r] = l_[r] * al[r] + rs[r];
      }
      #pragma unroll
      for (int dt = 0; dt < 4; ++dt)
        #pragma unroll
        for (int r = 0; r < 4; ++r) acc[dt][r] *= al[r];
      #pragma unroll
      for (int kc = 0; kc < 2; ++kc)
        #pragma unroll
        for (int r = 0; r < 4; ++r)
          Ps[(lhi * 4 + r) * 40 + kc * 16 + l15] = (bf16_t)s[kc][r];
      bf16x8 pa = *(const bf16x8*)&Ps[l15 * 40 + lhi * 8];
      #pragma unroll
      for (int dt = 0; dt < 4; ++dt) {
        bf16x8 bv = *(const bf16x8*)(Vt + (size_t)(dt * 16 + l15) * T_SEQ + k0 + lhi * 8);
        acc[dt] = __builtin_amdgcn_mfma_f32_16x16x32_bf16(pa, bv, acc[dt], 0, 0, 0);
      }
    }
    #pragma unroll
    for (int dt = 0; dt < 4; ++dt)
      #pragma unroll
      for (int r = 0; r < 4; ++r)
        y[(size_t)(b * T_SEQ + q0 + lhi * 4 + r) * CD + h * 64 + dt * 16 + l15] =
            (bf16_t)(acc[dt][r] / l_[r]);
  }
}

// ---------------------------------------------------------------- launcher
extern "C" void kernel_launch(void* const* d_in, const int* in_sizes, int n_in,
                              void* d_out, int out_size, void* d_ws, size_t ws_size,
                              hipStream_t stream) {
  const int*   idx   = (const int*)d_in[0];
  const float* wte   = (const float*)d_in[1];
  const float* wpe   = (const float*)d_in[2];
  const float* ln1w  = (const float*)d_in[3];
  const float* ln1b  = (const float*)d_in[4];
  const float* qkvw  = (const float*)d_in[5];
  const float* qkvb  = (const float*)d_in[6];
  const float* projw = (const float*)d_in[7];
  const float* projb = (const float*)d_in[8];
  const float* ln2w  = (const float*)d_in[9];
  const float* ln2b  = (const float*)d_in[10];
  const float* fcw   = (const float*)d_in[11];
  const float* fcb   = (const float*)d_in[12];
  const float* fcow  = (const float*)d_in[13];
  const float* fcob  = (const float*)d_in[14];
  const float* lnfw  = (const float*)d_in[15];
  const float* lnfb  = (const float*)d_in[16];
  float* out = (float*)d_out;

  char* w = (char*)d_ws;
  auto alloc = [&](size_t bytes) {
    char* p = w; w += (bytes + 255) & ~(size_t)255; return p;
  };
  float*  x    = (float*)alloc((size_t)M_ROWS * CD * 4);
  float*  x2   = (float*)alloc((size_t)M_ROWS * CD * 4);
  bf16_t* hb   = (bf16_t*)alloc((size_t)M_ROWS * CD * 2);
  bf16_t* qkvB = (bf16_t*)alloc((size_t)M_ROWS * 3 * CD * 2);
  bf16_t* yb   = (bf16_t*)alloc((size_t)M_ROWS * CD * 2);
  bf16_t* fca  = (bf16_t*)alloc((size_t)M_ROWS * 4 * CD * 2);
  bf16_t* VT   = (bf16_t*)alloc((size_t)2 * NH * 64 * T_SEQ * 2);
  bf16_t* wqT  = (bf16_t*)alloc((size_t)3 * CD * CD * 2);
  bf16_t* wpT  = (bf16_t*)alloc((size_t)CD * CD * 2);
  bf16_t* wfT  = (bf16_t*)alloc((size_t)4 * CD * CD * 2);
  bf16_t* woT  = (bf16_t*)alloc((size_t)CD * 4 * CD * 2);
  bf16_t* wteB = (bf16_t*)alloc((size_t)NV * CD * 2);

  embed_k<<<M_ROWS, 256, 0, stream>>>(idx, wte, wpe, x);
  {
    int n4 = NV * CD / 4;
    cvt_k<<<(n4 + 255) / 256, 256, 0, stream>>>(wte, wteB, n4);
  }

  for (int l = 0; l < NL; ++l) {
    transcvt_k<<<dim3(3 * CD / 32, CD / 32), 256, 0, stream>>>(qkvw  + (size_t)l * CD * 3 * CD, wqT, CD, 3 * CD);
    transcvt_k<<<dim3(CD / 32, CD / 32),     256, 0, stream>>>(projw + (size_t)l * CD * CD,     wpT, CD, CD);
    transcvt_k<<<dim3(4 * CD / 32, CD / 32), 256, 0, stream>>>(fcw   + (size_t)l * CD * 4 * CD, wfT, CD, 4 * CD);
    transcvt_k<<<dim3(CD / 32, 4 * CD / 32), 256, 0, stream>>>(fcow  + (size_t)l * 4 * CD * CD, woT, 4 * CD, CD);

    ln_k<<<M_ROWS, 256, 0, stream>>>(x, ln1w + l * CD, ln1b + l * CD, hb);
    gemm_bt<128, 128, 0, false><<<dim3(3 * CD / 128, M_ROWS / 128), 256, 0, stream>>>(
        hb, wqT, qkvb + l * 3 * CD, nullptr, qkvB, M_ROWS, 3 * CD, CD);
    vtrans_k<<<dim3(T_SEQ / 64, 2 * NH), 256, 0, stream>>>(qkvB, VT);
    attn_k<<<2 * NH * 32, 64, 0, stream>>>(qkvB, VT, yb);
    gemm_bt<64, 64, 2, false><<<dim3(CD / 64, M_ROWS / 64), 256, 0, stream>>>(
        yb, wpT, projb + l * CD, x, x2, M_ROWS, CD, CD);
    ln_k<<<M_ROWS, 256, 0, stream>>>(x2, ln2w + l * CD, ln2b + l * CD, hb);
    gemm_bt<128, 128, 1, false><<<dim3(4 * CD / 128, M_ROWS / 128), 256, 0, stream>>>(
        hb, wfT, fcb + l * 4 * CD, nullptr, fca, M_ROWS, 4 * CD, CD);
    gemm_bt<64, 64, 2, false><<<dim3(CD / 64, M_ROWS / 64), 256, 0, stream>>>(
        fca, woT, fcob + l * CD, x2, x, M_ROWS, CD, 4 * CD);
  }

  ln_k<<<M_ROWS, 256, 0, stream>>>(x, lnfw, lnfb, hb);
  gemm_bt<128, 128, 3, true><<<dim3(M_ROWS / 128, (NV + 127) / 128), 256, 0, stream>>>(
      hb, wteB, nullptr, nullptr, out, M_ROWS, NV, CD);
}

// Round 4
// 2407.252 us; speedup vs baseline: 9.4219x; 1.0737x over previous
//
#include <hip/hip_runtime.h>
#include <cmath>
#include <cstdint>

// GPT-2 (124M) forward: B=2, T=1024, C=768, H=12, L=12, V=50257, D=64
#define T_SEQ 1024
#define NH 12
#define NL 12
#define NV 50257
#define CD 768
#define M_ROWS 2048   // B*T

typedef __bf16 bf16_t;
typedef __bf16 bf16x8 __attribute__((ext_vector_type(8)));
typedef float f32x4 __attribute__((ext_vector_type(4)));

// async global->LDS, 16B per lane; LDS dest = wave-uniform base + lane*16
__device__ __forceinline__ void gload16(const bf16_t* g, bf16_t* l) {
  __builtin_amdgcn_global_load_lds(
      (const __attribute__((address_space(1))) void*)g,
      (__attribute__((address_space(3))) void*)l, 16, 0, 0);
}

// ---------------------------------------------------------------- embedding
__global__ __launch_bounds__(256) void embed_k(const int* __restrict__ idx,
    const float* __restrict__ wte, const float* __restrict__ wpe,
    float* __restrict__ x) {
  int m = blockIdx.x;
  int t = m & (T_SEQ - 1);
  int tok = idx[m];
  const float* a = wte + (size_t)tok * CD;
  const float* p = wpe + (size_t)t * CD;
  float* xr = x + (size_t)m * CD;
  int c = threadIdx.x;
  xr[c]       = a[c]       + p[c];
  xr[c + 256] = a[c + 256] + p[c + 256];
  xr[c + 512] = a[c + 512] + p[c + 512];
}

// ------------------------------------------------------- f32 -> bf16 convert
__global__ __launch_bounds__(256) void cvt_k(const float* __restrict__ in,
    bf16_t* __restrict__ out, int n4) {
  int i = blockIdx.x * 256 + threadIdx.x;
  if (i < n4) {
    float4 v = ((const float4*)in)[i];
    bf16_t* o = out + (size_t)i * 4;
    o[0] = (bf16_t)v.x; o[1] = (bf16_t)v.y;
    o[2] = (bf16_t)v.z; o[3] = (bf16_t)v.w;
  }
}

// ----------------------------------- W[K,N] f32  ->  WT[N,K] bf16 (transpose)
__global__ __launch_bounds__(256) void transcvt_k(const float* __restrict__ W,
    bf16_t* __restrict__ WT, int K, int N) {
  __shared__ float tl[32][33];
  int k0 = blockIdx.y * 32, n0 = blockIdx.x * 32;
  int j = threadIdx.x & 31, i0 = threadIdx.x >> 5;
  #pragma unroll
  for (int i = i0; i < 32; i += 8) tl[i][j] = W[(size_t)(k0 + i) * N + n0 + j];
  __syncthreads();
  #pragma unroll
  for (int i = i0; i < 32; i += 8)
    WT[(size_t)(n0 + i) * K + k0 + j] = (bf16_t)tl[j][i];
}

// ------------------------------------------------------------- LayerNorm
__global__ __launch_bounds__(256) void ln_k(const float* __restrict__ x,
    const float* __restrict__ w, const float* __restrict__ bi,
    bf16_t* __restrict__ out) {
  int row = blockIdx.x;
  const float* xr = x + (size_t)row * CD;
  int t = threadIdx.x;
  float v0 = xr[t], v1 = xr[t + 256], v2 = xr[t + 512];
  float s = v0 + v1 + v2;
  float ss = v0 * v0 + v1 * v1 + v2 * v2;
  #pragma unroll
  for (int o = 1; o < 64; o <<= 1) { s += __shfl_xor(s, o); ss += __shfl_xor(ss, o); }
  __shared__ float sh[8];
  int wid = t >> 6, lane = t & 63;
  if (lane == 0) { sh[wid] = s; sh[4 + wid] = ss; }
  __syncthreads();
  s  = sh[0] + sh[1] + sh[2] + sh[3];
  ss = sh[4] + sh[5] + sh[6] + sh[7];
  float mean = s * (1.f / CD);
  float var  = ss * (1.f / CD) - mean * mean;
  float rs = rsqrtf(var + 1e-5f);
  bf16_t* orow = out + (size_t)row * CD;
  orow[t]       = (bf16_t)((v0 - mean) * rs * w[t]       + bi[t]);
  orow[t + 256] = (bf16_t)((v1 - mean) * rs * w[t + 256] + bi[t + 256]);
  orow[t + 512] = (bf16_t)((v2 - mean) * rs * w[t + 512] + bi[t + 512]);
}

// ------------------------------------------------------------- GEMM (B^T)
// BK=64. EPI 0: +bias->bf16 | 1: gelu(+bias)->bf16 | 2: +bias+resid->f32 | 3: f32
// global_load_lds staging; chunk-XOR swizzle p = c ^ (r&7) over 8 16B-chunks/row,
// applied on the GLOBAL source (LDS dest linear) and on fragment reads (rule 21).
// XSWZ: XCD-chunked bijective block swizzle (requires nwg % 8 == 0).
template <int BM, int BN, int EPI, bool SWAP, bool XSWZ>
__global__ __launch_bounds__(256) void gemm_bt(
    const bf16_t* __restrict__ A,     // [M,K]
    const bf16_t* __restrict__ BT,    // [N,K]
    const float* __restrict__ bias,   // [N] or null
    const float* __restrict__ resid,  // [M,N] or null
    void* __restrict__ out_p,
    int Mdim, int Ndim, int Kdim) {
  constexpr int MR = BM / 32, NR = BN / 32;
  __shared__ __align__(1024) bf16_t As[BM * 64];
  __shared__ __align__(1024) bf16_t Bs[BN * 64];
  const int t = threadIdx.x;
  const int wid = t >> 6, lane = t & 63;
  const int wm = wid >> 1, wn = wid & 1;
  int bx = blockIdx.x, by = blockIdx.y;
  if (XSWZ) {
    int gx = gridDim.x;
    int lin = by * gx + bx;
    int cpx = (gx * gridDim.y) >> 3;
    int swz = (lin & 7) * cpx + (lin >> 3);
    bx = swz % gx; by = swz / gx;
  }
  const int m0 = (SWAP ? bx : by) * BM;
  const int n0 = (SWAP ? by : bx) * BN;
  const int l15 = lane & 15, lhi = lane >> 4;

  // staging geometry: each wave sweep = 8 rows x 8 chunks (1 KB, linear LDS)
  const int srow = lane >> 3;              // 0..7 within sweep
  const int schk = lane & 7;               // LDS chunk position

  f32x4 acc[MR][NR] = {};

  for (int kt = 0; kt < Kdim; kt += 64) {
    #pragma unroll
    for (int i = 0; i < BM / 32; ++i) {
      int rbase = wid * (BM / 4) + i * 8;
      int r = rbase + srow;
      int c = schk ^ (r & 7);
      gload16(A + (size_t)(m0 + r) * Kdim + kt + c * 8, As + rbase * 64);
    }
    #pragma unroll
    for (int i = 0; i < BN / 32; ++i) {
      int rbase = wid * (BN / 4) + i * 8;
      int r = rbase + srow;
      int nr = n0 + r; if (nr >= Ndim) nr = Ndim - 1;
      int c = schk ^ (r & 7);
      gload16(BT + (size_t)nr * Kdim + kt + c * 8, Bs + rbase * 64);
    }
    __syncthreads();

    #pragma unroll
    for (int ks = 0; ks < 2; ++ks) {
      bf16x8 af[MR], bfr[NR];
      #pragma unroll
      for (int mm = 0; mm < MR; ++mm) {
        int ra = wm * (BM / 2) + mm * 16 + l15;
        af[mm] = *(const bf16x8*)&As[ra * 64 + (((ks * 4 + lhi) ^ (ra & 7)) * 8)];
      }
      #pragma unroll
      for (int nn = 0; nn < NR; ++nn) {
        int rb = wn * (BN / 2) + nn * 16 + l15;
        bfr[nn] = *(const bf16x8*)&Bs[rb * 64 + (((ks * 4 + lhi) ^ (rb & 7)) * 8)];
      }
      #pragma unroll
      for (int mm = 0; mm < MR; ++mm)
        #pragma unroll
        for (int nn = 0; nn < NR; ++nn)
          acc[mm][nn] = __builtin_amdgcn_mfma_f32_16x16x32_bf16(af[mm], bfr[nn], acc[mm][nn], 0, 0, 0);
    }
    __syncthreads();
  }

  bf16_t* ob = (bf16_t*)out_p;
  float*  of = (float*)out_p;
  const int row0 = m0 + wm * (BM / 2);
  const int col0 = n0 + wn * (BN / 2);
  #pragma unroll
  for (int mm = 0; mm < MR; ++mm) {
    #pragma unroll
    for (int nn = 0; nn < NR; ++nn) {
      int col = col0 + nn * 16 + l15;
      if (col >= Ndim) continue;
      float bv = (EPI != 3) ? bias[col] : 0.f;
      #pragma unroll
      for (int r = 0; r < 4; ++r) {
        int row = row0 + mm * 16 + lhi * 4 + r;
        float v = acc[mm][nn][r] + bv;
        size_t o = (size_t)row * Ndim + col;
        if (EPI == 0) {
          ob[o] = (bf16_t)v;
        } else if (EPI == 1) {
          float u = v + 0.044715f * v * v * v;
          v = 0.5f * v * (1.f + tanhf(0.79788456080286536f * u));
          ob[o] = (bf16_t)v;
        } else if (EPI == 2) {
          of[o] = resid[o] + v;
        } else {
          of[o] = v;
        }
      }
    }
  }
}

// --------------------------------------------- V transpose: VT[bh][64][1024]
__global__ __launch_bounds__(256) void vtrans_k(const bf16_t* __restrict__ qkv,
                                                bf16_t* __restrict__ VT) {
  __shared__ __align__(16) bf16_t tl[64 * 72];
  const int bh = blockIdx.y;
  const int t0 = blockIdx.x * 64;
  const int b = bh / NH, h = bh % NH;
  const int tid = threadIdx.x;
  const int row = tid >> 2;
  const int seg = (tid & 3) * 16;

  const bf16_t* src = qkv + (size_t)(b * T_SEQ + t0 + row) * (3 * CD) + 2 * CD + h * 64 + seg;
  bf16x8 v0 = *(const bf16x8*)src;
  bf16x8 v1 = *(const bf16x8*)(src + 8);
  #pragma unroll
  for (int j = 0; j < 8; ++j) tl[(seg + j) * 72 + row] = v0[j];
  #pragma unroll
  for (int j = 0; j < 8; ++j) tl[(seg + 8 + j) * 72 + row] = v1[j];
  __syncthreads();

  bf16_t* dst = VT + ((size_t)bh * 64 + row) * T_SEQ + t0 + seg;
  *(bf16x8*)dst       = *(const bf16x8*)&tl[row * 72 + seg];
  *(bf16x8*)(dst + 8) = *(const bf16x8*)&tl[row * 72 + seg + 8];
}

// ------------------------------------------------------- MFMA flash attention
// 1 wave/block, one 16-row q-tile per block (unpaired for max concurrency).
__global__ __launch_bounds__(64) void attn_k(const bf16_t* __restrict__ qkv,
                                             const bf16_t* __restrict__ VT,
                                             bf16_t* __restrict__ y) {
  __shared__ __align__(16) bf16_t Ps[16 * 40];
  const int lane = threadIdx.x;
  const int gw = blockIdx.x;                 // 0 .. B*NH*64-1
  const int qi = gw & 63;
  const int bh = gw >> 6;
  const int h = bh % NH, b = bh / NH;
  const bf16_t* Qbase = qkv + (size_t)b * T_SEQ * (3 * CD) + h * 64;
  const bf16_t* Kbase = Qbase + CD;
  const bf16_t* Vt = VT + (size_t)bh * 64 * T_SEQ;

  const int l15 = lane & 15, lhi = lane >> 4;
  const int q0 = qi * 16;

  bf16x8 aq[2];
  #pragma unroll
  for (int c = 0; c < 2; ++c)
    aq[c] = *(const bf16x8*)(Qbase + (size_t)(q0 + l15) * (3 * CD) + c * 32 + lhi * 8);

  f32x4 acc[4] = {};
  float m_[4], l_[4];
  #pragma unroll
  for (int r = 0; r < 4; ++r) { m_[r] = -INFINITY; l_[r] = 0.f; }

  const int qrow = q0 + lhi * 4;
  const int nt = (q0 + 47) / 32;
  for (int kt = 0; kt < nt; ++kt) {
    const int k0 = kt * 32;
    f32x4 s[2] = {};
    #pragma unroll
    for (int c = 0; c < 2; ++c) {
      #pragma unroll
      for (int kc = 0; kc < 2; ++kc) {
        bf16x8 bk = *(const bf16x8*)(Kbase + (size_t)(k0 + kc * 16 + l15) * (3 * CD) + c * 32 + lhi * 8);
        s[kc] = __builtin_amdgcn_mfma_f32_16x16x32_bf16(aq[c], bk, s[kc], 0, 0, 0);
      }
    }
    float mx[4];
    #pragma unroll
    for (int r = 0; r < 4; ++r) mx[r] = -INFINITY;
    #pragma unroll
    for (int kc = 0; kc < 2; ++kc) {
      const int kcol = k0 + kc * 16 + l15;
      #pragma unroll
      for (int r = 0; r < 4; ++r) {
        float sv = (kcol <= qrow + r) ? s[kc][r] * 0.125f : -INFINITY;
        s[kc][r] = sv;
        mx[r] = fmaxf(mx[r], sv);
      }
    }
    #pragma unroll
    for (int r = 0; r < 4; ++r) {
      mx[r] = fmaxf(mx[r], __shfl_xor(mx[r], 1));
      mx[r] = fmaxf(mx[r], __shfl_xor(mx[r], 2));
      mx[r] = fmaxf(mx[r], __shfl_xor(mx[r], 4));
      mx[r] = fmaxf(mx[r], __shfl_xor(mx[r], 8));
    }
    float al[4], rs[4];
    #pragma unroll
    for (int r = 0; r < 4; ++r) {
      float mn = fmaxf(m_[r], mx[r]);
      al[r] = __expf(m_[r] - mn);
      m_[r] = mn;
      float p0 = __expf(s[0][r] - mn);
      float p1 = __expf(s[1][r] - mn);
      s[0][r] = p0; s[1][r] = p1;
      rs[r] = p0 + p1;
    }
    #pragma unroll
    for (int r = 0; r < 4; ++r) {
      rs[r] += __shfl_xor(rs[r], 1);
      rs[r] += __shfl_xor(rs[r], 2);
      rs[r] += __shfl_xor(rs[r], 4);
      rs[r] += __shfl_xor(rs[r], 8);
      l_[r] = l_[r] * al[r] + rs[r];
    }
    #pragma unroll
    for (int dt = 0; dt < 4; ++dt)
      #pragma unroll
      for (int r = 0; r < 4; ++r) acc[dt][r] *= al[r];
    #pragma unroll
    for (int kc = 0; kc < 2; ++kc)
      #pragma unroll
      for (int r = 0; r < 4; ++r)
        Ps[(lhi * 4 + r) * 40 + kc * 16 + l15] = (bf16_t)s[kc][r];
    bf16x8 pa = *(const bf16x8*)&Ps[l15 * 40 + lhi * 8];
    #pragma unroll
    for (int dt = 0; dt < 4; ++dt) {
      bf16x8 bv = *(const bf16x8*)(Vt + (size_t)(dt * 16 + l15) * T_SEQ + k0 + lhi * 8);
      acc[dt] = __builtin_amdgcn_mfma_f32_16x16x32_bf16(pa, bv, acc[dt], 0, 0, 0);
    }
  }
  #pragma unroll
  for (int dt = 0; dt < 4; ++dt)
    #pragma unroll
    for (int r = 0; r < 4; ++r)
      y[(size_t)(b * T_SEQ + q0 + lhi * 4 + r) * CD + h * 64 + dt * 16 + l15] =
          (bf16_t)(acc[dt][r] / l_[r]);
}

// ---------------------------------------------------------------- launcher
extern "C" void kernel_launch(void* const* d_in, const int* in_sizes, int n_in,
                              void* d_out, int out_size, void* d_ws, size_t ws_size,
                              hipStream_t stream) {
  const int*   idx   = (const int*)d_in[0];
  const float* wte   = (const float*)d_in[1];
  const float* wpe   = (const float*)d_in[2];
  const float* ln1w  = (const float*)d_in[3];
  const float* ln1b  = (const float*)d_in[4];
  const float* qkvw  = (const float*)d_in[5];
  const float* qkvb  = (const float*)d_in[6];
  const float* projw = (const float*)d_in[7];
  const float* projb = (const float*)d_in[8];
  const float* ln2w  = (const float*)d_in[9];
  const float* ln2b  = (const float*)d_in[10];
  const float* fcw   = (const float*)d_in[11];
  const float* fcb   = (const float*)d_in[12];
  const float* fcow  = (const float*)d_in[13];
  const float* fcob  = (const float*)d_in[14];
  const float* lnfw  = (const float*)d_in[15];
  const float* lnfb  = (const float*)d_in[16];
  float* out = (float*)d_out;

  char* w = (char*)d_ws;
  auto alloc = [&](size_t bytes) {
    char* p = w; w += (bytes + 255) & ~(size_t)255; return p;
  };
  float*  x    = (float*)alloc((size_t)M_ROWS * CD * 4);
  float*  x2   = (float*)alloc((size_t)M_ROWS * CD * 4);
  bf16_t* hb   = (bf16_t*)alloc((size_t)M_ROWS * CD * 2);
  bf16_t* qkvB = (bf16_t*)alloc((size_t)M_ROWS * 3 * CD * 2);
  bf16_t* yb   = (bf16_t*)alloc((size_t)M_ROWS * CD * 2);
  bf16_t* fca  = (bf16_t*)alloc((size_t)M_ROWS * 4 * CD * 2);
  bf16_t* VT   = (bf16_t*)alloc((size_t)2 * NH * 64 * T_SEQ * 2);
  bf16_t* wqT  = (bf16_t*)alloc((size_t)3 * CD * CD * 2);
  bf16_t* wpT  = (bf16_t*)alloc((size_t)CD * CD * 2);
  bf16_t* wfT  = (bf16_t*)alloc((size_t)4 * CD * CD * 2);
  bf16_t* woT  = (bf16_t*)alloc((size_t)CD * 4 * CD * 2);
  bf16_t* wteB = (bf16_t*)alloc((size_t)NV * CD * 2);

  embed_k<<<M_ROWS, 256, 0, stream>>>(idx, wte, wpe, x);
  {
    int n4 = NV * CD / 4;
    cvt_k<<<(n4 + 255) / 256, 256, 0, stream>>>(wte, wteB, n4);
  }

  for (int l = 0; l < NL; ++l) {
    transcvt_k<<<dim3(3 * CD / 32, CD / 32), 256, 0, stream>>>(qkvw  + (size_t)l * CD * 3 * CD, wqT, CD, 3 * CD);
    transcvt_k<<<dim3(CD / 32, CD / 32),     256, 0, stream>>>(projw + (size_t)l * CD * CD,     wpT, CD, CD);
    transcvt_k<<<dim3(4 * CD / 32, CD / 32), 256, 0, stream>>>(fcw   + (size_t)l * CD * 4 * CD, wfT, CD, 4 * CD);
    transcvt_k<<<dim3(CD / 32, 4 * CD / 32), 256, 0, stream>>>(fcow  + (size_t)l * 4 * CD * CD, woT, 4 * CD, CD);

    ln_k<<<M_ROWS, 256, 0, stream>>>(x, ln1w + l * CD, ln1b + l * CD, hb);
    gemm_bt<128, 128, 0, false, false><<<dim3(3 * CD / 128, M_ROWS / 128), 256, 0, stream>>>(
        hb, wqT, qkvb + l * 3 * CD, nullptr, qkvB, M_ROWS, 3 * CD, CD);
    vtrans_k<<<dim3(T_SEQ / 64, 2 * NH), 256, 0, stream>>>(qkvB, VT);
    attn_k<<<2 * NH * 64, 64, 0, stream>>>(qkvB, VT, yb);
    gemm_bt<64, 64, 2, false, false><<<dim3(CD / 64, M_ROWS / 64), 256, 0, stream>>>(
        yb, wpT, projb + l * CD, x, x2, M_ROWS, CD, CD);
    ln_k<<<M_ROWS, 256, 0, stream>>>(x2, ln2w + l * CD, ln2b + l * CD, hb);
    gemm_bt<128, 128, 1, false, false><<<dim3(4 * CD / 128, M_ROWS / 128), 256, 0, stream>>>(
        hb, wfT, fcb + l * 4 * CD, nullptr, fca, M_ROWS, 4 * CD, CD);
    gemm_bt<64, 64, 2, false, false><<<dim3(CD / 64, M_ROWS / 64), 256, 0, stream>>>(
        fca, woT, fcob + l * CD, x2, x, M_ROWS, CD, 4 * CD);
  }

  ln_k<<<M_ROWS, 256, 0, stream>>>(x, lnfw, lnfb, hb);
  gemm_bt<128, 128, 3, true, true><<<dim3(M_ROWS / 128, (NV + 127) / 128), 256, 0, stream>>>(
      hb, wteB, nullptr, nullptr, out, M_ROWS, NV, CD);
}